// Round 1
// baseline (532.617 us; speedup 1.0000x reference)
//
#include <hip/hip_runtime.h>

// Conv2d: data [32,1,224,224] f32, weight [64,1,3,3] f32 -> out [32,64,222,222] f32
// VALID, stride 1, cross-correlation. Write-BW bound (403.7 MB out).
//
// R1 lesson: channel in the grid -> wave-uniform weights in SGPRs, contiguous
//   per-wave write runs.
// R2 theory: timed dur = harness re-poison fill (~267us) + conv (~169us).
//   Conv's 2.5x gap to the write roofline is READ traffic: 72 B of input per
//   8 outputs (2 ch/thread) = up to 925 MB of read demand vs a 6.4 MB input,
//   re-fetched from HBM because the 404 MB write stream thrashes L2.
//   Fix: (a) 8 channels per thread -> reads per output / 4 (<=231 MB even
//   uncached); (b) nontemporal stores -> write stream stops evicting the
//   input from L2, so reads become L2 hits.

#define IN_H 224
#define IN_W 224
#define OUT_H 222
#define OUT_W 222
#define OUT_C 64
#define BATCH 32
#define XG 56                       // groups of 4 outputs along x (last group: 2)
#define PLANE (OUT_H * OUT_W)       // 49284
#define THREADS_PER_PLANE (OUT_H * XG)  // 12432
#define CPT 8                       // channels per thread

typedef float v2f __attribute__((ext_vector_type(2)));

__global__ __launch_bounds__(256) void conv3x3_kernel(
    const float* __restrict__ in, const float* __restrict__ wt,
    float* __restrict__ out) {
  const int t = blockIdx.x * blockDim.x + threadIdx.x;
  if (t >= THREADS_PER_PLANE) return;
  const int xg = t % XG;
  const int y  = t / XG;
  const int x  = xg * 4;
  const int b  = blockIdx.z;
  const int ch0 = blockIdx.y * CPT;          // wave-uniform channel group

  // Input patch rows y..y+2, cols x..x+5. Base index b*50176 + y*224 + x,
  // all terms %4==0 -> float4 is 16B aligned; +4 float2 is 8B aligned.
  const float* ip = in + ((size_t)b * IN_H + y) * IN_W + x;
  const float4 a0 = *(const float4*)(ip);
  const float4 a1 = *(const float4*)(ip + IN_W);
  const float4 a2 = *(const float4*)(ip + 2 * IN_W);

  const bool full = (xg != XG - 1);          // tail group (x=220): only 2 outputs
  float e00 = 0.f, e01 = 0.f, e10 = 0.f, e11 = 0.f, e20 = 0.f, e21 = 0.f;
  if (full) {
    const float2 e0 = *(const float2*)(ip + 4);
    const float2 e1 = *(const float2*)(ip + IN_W + 4);
    const float2 e2 = *(const float2*)(ip + 2 * IN_W + 4);
    e00 = e0.x; e01 = e0.y; e10 = e1.x; e11 = e1.y; e20 = e2.x; e21 = e2.y;
  }

  const float rin[3][6] = {
    {a0.x, a0.y, a0.z, a0.w, e00, e01},
    {a1.x, a1.y, a1.z, a1.w, e10, e11},
    {a2.x, a2.y, a2.z, a2.w, e20, e21},
  };

  float* op = out + (size_t)(b * OUT_C + ch0) * PLANE + (size_t)y * OUT_W + x;

  #pragma unroll
  for (int c = 0; c < CPT; ++c) {
    const float* w = wt + (ch0 + c) * 9;     // uniform address -> s_load / SGPRs
    float o[4] = {0.f, 0.f, 0.f, 0.f};
    #pragma unroll
    for (int r = 0; r < 3; ++r) {
      #pragma unroll
      for (int k = 0; k < 3; ++k) {
        const float wv = w[r * 3 + k];
        #pragma unroll
        for (int j = 0; j < 4; ++j)
          o[j] = fmaf(rin[r][j + k], wv, o[j]);
      }
    }
    // Output base: (b*64+ch)*49284 + y*222 + x -> even -> 8B aligned.
    // Nontemporal: 404 MB streaming write must not evict the 6.4 MB input
    // from L2 (read re-fetch was the R2 bottleneck theory).
    v2f lo = {o[0], o[1]};
    __builtin_nontemporal_store(lo, (v2f*)op);
    if (full) {
      v2f hi = {o[2], o[3]};
      __builtin_nontemporal_store(hi, (v2f*)(op + 2));
    }
    op += PLANE;
  }
}

extern "C" void kernel_launch(void* const* d_in, const int* in_sizes, int n_in,
                              void* d_out, int out_size, void* d_ws, size_t ws_size,
                              hipStream_t stream) {
  const float* data   = (const float*)d_in[0];
  const float* weight = (const float*)d_in[1];
  float* out = (float*)d_out;

  dim3 grid((THREADS_PER_PLANE + 255) / 256, OUT_C / CPT, BATCH);
  conv3x3_kernel<<<grid, 256, 0, stream>>>(data, weight, out);
}

// Round 2
// 426.896 us; speedup vs baseline: 1.2477x; 1.2477x over previous
//
#include <hip/hip_runtime.h>

// Conv2d: data [32,1,224,224] f32, weight [64,1,3,3] f32 -> out [32,64,222,222] f32
// VALID, stride 1, cross-correlation. Write-BW bound (403.7 MB out).
//
// R1 lesson: channel pair in grid.y -> wave-uniform weights (SGPRs), per-wave
//   contiguous write runs, consecutive blocks -> consecutive rows. 436 us.
// R2 lesson: CPT=8 + nontemporal regressed to 533 us. 8 plane-strided write
//   runs per wave re-scattered the stream; nt bypassed L2 write-combining on
//   8B misaligned stores. Input reads are L2/L3-resident and were never the
//   HBM bottleneck. Reverted both.
// R3: flat-plane decomposition. Plane base (b*64+ch)*49284*4 B is 16B-aligned
//   and plane size is a multiple of float4, so each thread stores ONE aligned
//   float4 per channel (2 stores vs 4 float2), and each wave writes a dense
//   1KB run of fully-covered 64B lines. Row straddle handled uniformly: the
//   float4 = two independent float2 halves, each gathered by three 4-wide
//   dword-aligned row loads (no branches).

#define IN_H 224
#define IN_W 224
#define OUT_H 222
#define OUT_W 222
#define OUT_C 64
#define BATCH 32
#define PLANE (OUT_H * OUT_W)      // 49284 floats, 197136 B (16B-aligned size)
#define G4 (PLANE / 4)             // 12321 float4 groups per plane

typedef float v4f __attribute__((ext_vector_type(4)));
struct __attribute__((aligned(8))) v4u8 { v4f v; };   // 8B-aligned float4 view

__global__ __launch_bounds__(256) void conv3x3_kernel(
    const float* __restrict__ in, const float* __restrict__ wt,
    float* __restrict__ out) {
  const unsigned tid = blockIdx.x * blockDim.x + threadIdx.x;  // float4 group in plane
  if (tid >= G4) return;
  const int b   = blockIdx.z;
  const int ch0 = blockIdx.y * 2;            // wave-uniform channel pair

  const unsigned f0 = tid * 4u;              // flat output index in plane
  const unsigned fB = f0 + 2u;
  const unsigned yA = f0 / 222u;             // magic-mul division
  const unsigned xA = f0 - yA * 222u;        // even, 0..220
  const unsigned yB = fB / 222u;
  const unsigned xB = fB - yB * 222u;        // even, 0..220

  // Input windows: rows y..y+2, cols x..x+3 (x<=220 -> max col 223, in range).
  // Byte addresses are 8B-aligned (all index terms even).
  const float* ibase = in + (size_t)b * (IN_H * IN_W);
  const float* pA = ibase + yA * IN_W + xA;
  const float* pB = ibase + yB * IN_W + xB;
  const v4f A0 = ((const v4u8*)(pA))->v;
  const v4f A1 = ((const v4u8*)(pA + IN_W))->v;
  const v4f A2 = ((const v4u8*)(pA + 2 * IN_W))->v;
  const v4f B0 = ((const v4u8*)(pB))->v;
  const v4f B1 = ((const v4u8*)(pB + IN_W))->v;
  const v4f B2 = ((const v4u8*)(pB + 2 * IN_W))->v;

  float* op = out + (size_t)(b * OUT_C + ch0) * PLANE + f0;  // 16B-aligned

  #pragma unroll
  for (int c = 0; c < 2; ++c) {
    const float* w = wt + (ch0 + c) * 9;     // uniform -> s_load into SGPRs
    const float w00 = w[0], w01 = w[1], w02 = w[2];
    const float w10 = w[3], w11 = w[4], w12 = w[5];
    const float w20 = w[6], w21 = w[7], w22 = w[8];

    float o0, o1, o2, o3;
    o0 = fmaf(A0.x, w00, fmaf(A0.y, w01, A0.z * w02));
    o0 = fmaf(A1.x, w10, fmaf(A1.y, w11, fmaf(A1.z, w12, o0)));
    o0 = fmaf(A2.x, w20, fmaf(A2.y, w21, fmaf(A2.z, w22, o0)));

    o1 = fmaf(A0.y, w00, fmaf(A0.z, w01, A0.w * w02));
    o1 = fmaf(A1.y, w10, fmaf(A1.z, w11, fmaf(A1.w, w12, o1)));
    o1 = fmaf(A2.y, w20, fmaf(A2.z, w21, fmaf(A2.w, w22, o1)));

    o2 = fmaf(B0.x, w00, fmaf(B0.y, w01, B0.z * w02));
    o2 = fmaf(B1.x, w10, fmaf(B1.y, w11, fmaf(B1.z, w12, o2)));
    o2 = fmaf(B2.x, w20, fmaf(B2.y, w21, fmaf(B2.z, w22, o2)));

    o3 = fmaf(B0.y, w00, fmaf(B0.z, w01, B0.w * w02));
    o3 = fmaf(B1.y, w10, fmaf(B1.z, w11, fmaf(B1.w, w12, o3)));
    o3 = fmaf(B2.y, w20, fmaf(B2.z, w21, fmaf(B2.w, w22, o3)));

    v4f o = {o0, o1, o2, o3};
    *(v4f*)op = o;                           // single 16B-aligned store
    op += PLANE;
  }
}

extern "C" void kernel_launch(void* const* d_in, const int* in_sizes, int n_in,
                              void* d_out, int out_size, void* d_ws, size_t ws_size,
                              hipStream_t stream) {
  const float* data   = (const float*)d_in[0];
  const float* weight = (const float*)d_in[1];
  float* out = (float*)d_out;

  dim3 grid((G4 + 255) / 256, OUT_C / 2, BATCH);
  conv3x3_kernel<<<grid, 256, 0, stream>>>(data, weight, out);
}

// Round 3
// 410.719 us; speedup vs baseline: 1.2968x; 1.0394x over previous
//
#include <hip/hip_runtime.h>

// Conv2d: data [32,1,224,224] f32, weight [64,1,3,3] f32 -> out [32,64,222,222] f32
// VALID, stride 1, cross-correlation. Write-BW bound (403.7 MB out).
//
// R1 lesson: channel group in grid.y -> wave-uniform weights (SGPRs), per-wave
//   contiguous write runs. 436 us.
// R2 lesson (re-read): CPT=8 + 8B NONTEMPORAL stores -> 533 us. The nt stores
//   bypassed L2 write-combining (partial-line HBM writes) — that alone explains
//   the regression; CPT=8 was confounded, not convicted.
// R3 lesson: perfect store micro-structure (one aligned float4 per channel,
//   dense full-line wave runs) moved only -2% (427 us, conv ~162 us vs ~66 us
//   write roofline). Stores are exonerated as the limiter.
// R4 theory: limiter is input re-read traffic. At CPT=2, reads request ~1.2 GB
//   (96 B per 32 B out) vs a 6.4 MB input, and the 404 MB write stream flushes
//   the 256 MB L3 every pass while the 32 ch-pair passes over an input region
//   are NOT concurrent -> HBM re-fetch + read/write turnaround. CPT=8 makes all
//   8 channel groups of a batch concurrent (one HBM fetch serves all) and cuts
//   read requests 4x. Stores stay normal cached float4 (the R2 fix).

#define IN_H 224
#define IN_W 224
#define OUT_H 222
#define OUT_W 222
#define OUT_C 64
#define BATCH 32
#define PLANE (OUT_H * OUT_W)      // 49284 floats, 197136 B (16B-aligned size)
#define G4 (PLANE / 4)             // 12321 float4 groups per plane
#define CPT 8                      // channels per thread

typedef float v4f __attribute__((ext_vector_type(4)));
struct __attribute__((aligned(8))) v4u8 { v4f v; };   // 8B-aligned float4 view

__global__ __launch_bounds__(256) void conv3x3_kernel(
    const float* __restrict__ in, const float* __restrict__ wt,
    float* __restrict__ out) {
  const unsigned tid = blockIdx.x * blockDim.x + threadIdx.x;  // float4 group in plane
  if (tid >= G4) return;
  const int b   = blockIdx.z;
  const int ch0 = blockIdx.y * CPT;          // wave-uniform channel group

  const unsigned f0 = tid * 4u;              // flat output index in plane
  const unsigned fB = f0 + 2u;
  const unsigned yA = f0 / 222u;             // magic-mul division
  const unsigned xA = f0 - yA * 222u;        // even, 0..220
  const unsigned yB = fB / 222u;
  const unsigned xB = fB - yB * 222u;        // even, 0..220

  // Input windows: rows y..y+2, cols x..x+3 (x<=220 -> max col 223, in range).
  // Byte addresses are 8B-aligned (all index terms even).
  const float* ibase = in + (size_t)b * (IN_H * IN_W);
  const float* pA = ibase + yA * IN_W + xA;
  const float* pB = ibase + yB * IN_W + xB;
  const v4f A0 = ((const v4u8*)(pA))->v;
  const v4f A1 = ((const v4u8*)(pA + IN_W))->v;
  const v4f A2 = ((const v4u8*)(pA + 2 * IN_W))->v;
  const v4f B0 = ((const v4u8*)(pB))->v;
  const v4f B1 = ((const v4u8*)(pB + IN_W))->v;
  const v4f B2 = ((const v4u8*)(pB + 2 * IN_W))->v;

  float* op = out + (size_t)(b * OUT_C + ch0) * PLANE + f0;  // 16B-aligned

  #pragma unroll
  for (int c = 0; c < CPT; ++c) {
    const float* w = wt + (ch0 + c) * 9;     // uniform -> s_load into SGPRs
    const float w00 = w[0], w01 = w[1], w02 = w[2];
    const float w10 = w[3], w11 = w[4], w12 = w[5];
    const float w20 = w[6], w21 = w[7], w22 = w[8];

    float o0, o1, o2, o3;
    o0 = fmaf(A0.x, w00, fmaf(A0.y, w01, A0.z * w02));
    o0 = fmaf(A1.x, w10, fmaf(A1.y, w11, fmaf(A1.z, w12, o0)));
    o0 = fmaf(A2.x, w20, fmaf(A2.y, w21, fmaf(A2.z, w22, o0)));

    o1 = fmaf(A0.y, w00, fmaf(A0.z, w01, A0.w * w02));
    o1 = fmaf(A1.y, w10, fmaf(A1.z, w11, fmaf(A1.w, w12, o1)));
    o1 = fmaf(A2.y, w20, fmaf(A2.z, w21, fmaf(A2.w, w22, o1)));

    o2 = fmaf(B0.x, w00, fmaf(B0.y, w01, B0.z * w02));
    o2 = fmaf(B1.x, w10, fmaf(B1.y, w11, fmaf(B1.z, w12, o2)));
    o2 = fmaf(B2.x, w20, fmaf(B2.y, w21, fmaf(B2.z, w22, o2)));

    o3 = fmaf(B0.y, w00, fmaf(B0.z, w01, B0.w * w02));
    o3 = fmaf(B1.y, w10, fmaf(B1.z, w11, fmaf(B1.w, w12, o3)));
    o3 = fmaf(B2.y, w20, fmaf(B2.z, w21, fmaf(B2.w, w22, o3)));

    v4f o = {o0, o1, o2, o3};
    *(v4f*)op = o;                           // single 16B-aligned cached store
    op += PLANE;
  }
}

extern "C" void kernel_launch(void* const* d_in, const int* in_sizes, int n_in,
                              void* d_out, int out_size, void* d_ws, size_t ws_size,
                              hipStream_t stream) {
  const float* data   = (const float*)d_in[0];
  const float* weight = (const float*)d_in[1];
  float* out = (float*)d_out;

  dim3 grid((G4 + 255) / 256, OUT_C / CPT, BATCH);
  conv3x3_kernel<<<grid, 256, 0, stream>>>(data, weight, out);
}